// Round 5
// baseline (4656.934 us; speedup 1.0000x reference)
//
#include <hip/hip_runtime.h>
#include <hip/hip_bf16.h>
#include <math.h>

#define NN 50000
#define EE 800000
#define HH 128
#define CHH 64
#define LL 3
#define ZT (NN * HH)
#define GNB 8
#define NB 16

using bf16 = __hip_bfloat16;
typedef unsigned short u16;
typedef unsigned int u32;

__device__ __forceinline__ float ldbf(const u16* p, size_t i) {
    return __uint_as_float(((u32)p[i]) << 16);
}
__device__ __forceinline__ void stbf(u16* p, size_t i, float v) {
    bf16 b = __float2bfloat16(v);
    p[i] = *reinterpret_cast<u16*>(&b);
}

// ---- zero-fill fallback (diagnostic: output2 would fail at exactly 49920) ----
__global__ __launch_bounds__(256) void zero_out_k(float* __restrict__ out, int n) {
    int i = blockIdx.x * 256 + threadIdx.x;
    if (i < n) out[i] = 0.f;
}

// ---- init: h = bf16(x), reset flags ----
__global__ __launch_bounds__(256) void init_k(const float* __restrict__ x, u16* __restrict__ h,
        int* __restrict__ deg, int* __restrict__ degns, int* __restrict__ softex,
        int* __restrict__ hardex, int* __restrict__ exitl, int* __restrict__ act) {
    int i = blockIdx.x * 256 + threadIdx.x;
    if (i < ZT) stbf(h, (size_t)i, x[i]);
    if (i < NN) { deg[i] = 1; degns[i] = 0; softex[i] = 0; hardex[i] = 0; exitl[i] = LL; }
    if (i < LL) act[i] = 0;
}

// ---- degrees (int atomics, exact) ----
__global__ __launch_bounds__(256) void degree_k(const int* __restrict__ ei,
        int* __restrict__ deg, int* __restrict__ degns) {
    int e = blockIdx.x * 256 + threadIdx.x;
    if (e >= EE) return;
    int s = ei[e], d = ei[EE + e];
    if ((u32)s >= NN || (u32)d >= NN) return;   // containment guard
    atomicAdd(&deg[d], 1);
    if (s != d) atomicAdd(&degns[s], 1);
}

// ---- scatter: agg[dst] += norm*h[src]; agg = f32 region inside d_out ----
__global__ __launch_bounds__(256) void scatter_f32_k(const int* __restrict__ ei, const u16* __restrict__ h,
        const int* __restrict__ deg, float* __restrict__ agg) {
    int tid = blockIdx.x * 256 + threadIdx.x;
    int e = tid >> 5;                 // 32 lanes/edge, 4 channels/lane
    if (e >= EE) return;
    int lane = tid & 31;
    int s = ei[e], d = ei[EE + e];
    if ((u32)s >= NN || (u32)d >= NN) return;
    float nrm = 1.0f / sqrtf((float)deg[s] * (float)deg[d]);
    size_t sb = (size_t)s * HH + lane * 4, db = (size_t)d * HH + lane * 4;
    const ushort4 hv = *(const ushort4*)(h + sb);
    atomicAdd(&agg[db + 0], nrm * __uint_as_float(((u32)hv.x) << 16));
    atomicAdd(&agg[db + 1], nrm * __uint_as_float(((u32)hv.y) << 16));
    atomicAdd(&agg[db + 2], nrm * __uint_as_float(((u32)hv.z) << 16));
    atomicAdd(&agg[db + 3], nrm * __uint_as_float(((u32)hv.w) << 16));
}

// ---- fused conv finish: h = act((agg + h/deg) @ W + b), in place (bf16 h) ----
__global__ __launch_bounds__(128) void gemm_fin_k(int geluf, u16* __restrict__ h,
        const float* __restrict__ agg, const int* __restrict__ deg,
        const float* __restrict__ W, const float* __restrict__ b) {
    int bn = blockIdx.x * GNB;
    int o = threadIdx.x;
    __shared__ float c[GNB][HH];
    #pragma unroll
    for (int m = 0; m < GNB; ++m) {
        int n = bn + m;
        if (n < NN) c[m][o] = agg[(size_t)n * HH + o] + ldbf(h, (size_t)n * HH + o) / (float)deg[n];
    }
    __syncthreads();
    float acc[GNB];
    float bias = b[o];
    #pragma unroll
    for (int m = 0; m < GNB; ++m) acc[m] = bias;
    for (int k = 0; k < HH; ++k) {
        float w = W[k * HH + o];
        #pragma unroll
        for (int m = 0; m < GNB; ++m) acc[m] = fmaf(c[m][k], w, acc[m]);
    }
    #pragma unroll
    for (int m = 0; m < GNB; ++m) {
        int n = bn + m;
        if (n < NN) {
            float v = acc[m];
            if (geluf) v = 0.5f * v * (1.0f + erff(v * 0.70710678118654752f));
            stbf(h, (size_t)n * HH + o, v);
        }
    }
}

// ---- soft-exit head (temp>0 & softmax monotone -> compare raw logits+gumbel) ----
__global__ __launch_bounds__(64) void soft_head_k(int li, const u16* __restrict__ h,
        const float* __restrict__ w1, const float* __restrict__ b1,
        const float* __restrict__ w2, const float* __restrict__ b2,
        const float* __restrict__ gs, int* __restrict__ softex,
        const int* __restrict__ hardex, int* __restrict__ act) {
    int bn = blockIdx.x * NB;
    int j = threadIdx.x;
    __shared__ float sh[NB][HH];
    for (int t = j; t < NB * HH; t += 64) {
        int m = t >> 7, k = t & 127, n = bn + m;
        sh[m][k] = (n < NN) ? ldbf(h, (size_t)n * HH + k) : 0.f;
    }
    __syncthreads();
    float acc[NB];
    float b1j = b1[j];
    #pragma unroll
    for (int m = 0; m < NB; ++m) acc[m] = b1j;
    for (int k = 0; k < HH; ++k) {
        float w = w1[k * CHH + j];
        #pragma unroll
        for (int m = 0; m < NB; ++m) acc[m] = fmaf(sh[m][k], w, acc[m]);
    }
    __shared__ float hid[NB][CHH + 1];
    #pragma unroll
    for (int m = 0; m < NB; ++m) hid[m][j] = fmaxf(acc[m], 0.f);
    __syncthreads();
    if (j < NB) {
        int n = bn + j;
        if (n < NN) {
            float l0 = b2[0], l1 = b2[1];
            for (int t = 0; t < CHH; ++t) {
                float hv = hid[j][t];
                l0 = fmaf(hv, w2[t * 2], l0);
                l1 = fmaf(hv, w2[t * 2 + 1], l1);
            }
            const float* g = gs + ((size_t)li * NN + n) * 2;
            if (l1 + g[1] > l0 + g[0]) softex[n] = 1;
            if (!hardex[n]) atomicAdd(&act[li], 1);  // active counted before this layer's hard exits
        }
    }
}

// ---- readiness scatter (int atomics) ----
__global__ __launch_bounds__(256) void ready_k(const int* __restrict__ ei,
        const int* __restrict__ softex, int* __restrict__ ready) {
    int e = blockIdx.x * 256 + threadIdx.x;
    if (e >= EE) return;
    int s = ei[e], d = ei[EE + e];
    if ((u32)s >= NN || (u32)d >= NN) return;
    if (s != d && softex[d]) atomicAdd(&ready[s], 1);
}

// ---- hard-exit head; exited rows snapshot into bf16 z_ws ----
__global__ __launch_bounds__(64) void hard_head_k(int li, const u16* __restrict__ h,
        const float* __restrict__ w1, const float* __restrict__ b1,
        const float* __restrict__ w2, const float* __restrict__ b2,
        const float* __restrict__ gh, const int* __restrict__ softex,
        int* __restrict__ hardex, int* __restrict__ exitl,
        const int* __restrict__ ready, const int* __restrict__ degns,
        u16* __restrict__ zws) {
    int bn = blockIdx.x * NB;
    int j = threadIdx.x;
    __shared__ int elig[NB];
    __shared__ float rd[NB];
    if (j < NB) {
        int n = bn + j;
        int e = (n < NN) && softex[n] && !hardex[n];  // non-soft-exited never hard-exit (1e6 margin)
        elig[j] = e;
        float r = 0.f;
        if (e) {
            int dns = degns[n]; if (dns < 1) dns = 1;
            r = (float)ready[n] / (float)dns;
        }
        rd[j] = r;
    }
    __syncthreads();
    int any = 0;
    #pragma unroll
    for (int m = 0; m < NB; ++m) any |= elig[m];
    if (!any) return;
    __shared__ float sh[NB][HH];
    for (int t = j; t < NB * HH; t += 64) {
        int m = t >> 7, k = t & 127, n = bn + m;
        sh[m][k] = elig[m] ? ldbf(h, (size_t)n * HH + k) : 0.f;
    }
    __syncthreads();
    float acc[NB];
    float b1j = b1[j];
    #pragma unroll
    for (int m = 0; m < NB; ++m) acc[m] = b1j;
    for (int k = 0; k < HH; ++k) {
        float w = w1[k * CHH + j];
        #pragma unroll
        for (int m = 0; m < NB; ++m) acc[m] = fmaf(sh[m][k], w, acc[m]);
    }
    float wr = w1[HH * CHH + j];  // readiness row of the [129][64] weight
    #pragma unroll
    for (int m = 0; m < NB; ++m) acc[m] = fmaf(rd[m], wr, acc[m]);
    __shared__ float hid[NB][CHH + 1];
    __shared__ int ex[NB];
    #pragma unroll
    for (int m = 0; m < NB; ++m) hid[m][j] = fmaxf(acc[m], 0.f);
    if (j < NB) ex[j] = 0;
    __syncthreads();
    if (j < NB) {
        int n = bn + j;
        if (elig[j]) {
            float l0 = b2[0], l1 = b2[1];
            for (int t = 0; t < CHH; ++t) {
                float hv = hid[j][t];
                l0 = fmaf(hv, w2[t * 2], l0);
                l1 = fmaf(hv, w2[t * 2 + 1], l1);
            }
            const float* g = gh + ((size_t)li * NN + n) * 2;
            if (l1 + g[1] > l0 + g[0]) { ex[j] = 1; hardex[n] = 1; exitl[n] = li; }
        }
    }
    __syncthreads();
    #pragma unroll
    for (int m = 0; m < NB; ++m) {
        if (ex[m]) {
            int n = bn + m;
            for (int k = j; k < HH; k += 64)
                stbf(zws, (size_t)n * HH + k, sh[m][k]);
        }
    }
}

// ---- tail: f32 outputs — z | exit_layers | active ----
__global__ __launch_bounds__(256) void tail_k(const u16* __restrict__ h, const u16* __restrict__ zws,
        const int* __restrict__ hardex, const int* __restrict__ exitl, const int* __restrict__ act,
        float* __restrict__ out) {
    int i = blockIdx.x * 256 + threadIdx.x;
    if (i < ZT) {
        int n = i >> 7;
        out[i] = hardex[n] ? ldbf(zws, (size_t)i) : ldbf(h, (size_t)i);
    } else if (i < ZT + NN) {
        out[i] = (float)exitl[i - ZT];
    } else if (i < ZT + NN + LL) {
        out[i] = (float)act[i - ZT - NN];
    }
}

extern "C" void kernel_launch(void* const* d_in, const int* in_sizes, int n_in,
                              void* d_out, int out_size, void* d_ws, size_t ws_size,
                              hipStream_t stream) {
    float* out = (float*)d_out;                 // OUTPUT IS FLOAT32 (ref returns f32/int32)
    const int OUT_N = ZT + NN + LL;

    // ---- input-slot mapping with verification against in_sizes ----
    static const int CANON[19] = {6400000,1600000,300000,300000,16384,128,16384,128,16384,128,
                                  8192,64,128,2,8256,64,128,2,128};
    static const int SORTED_ROLE[19] = {5,7,9,4,6,8,1,3,2,15,17,14,16,11,13,10,12,18,0};
    int perm[19];
    bool ok = (n_in == 19);
    if (ok) {
        bool mc = true, mr = true, ms = true;
        for (int i = 0; i < 19; ++i) {
            if (in_sizes[i] != CANON[i]) mc = false;
            if (in_sizes[i] != CANON[18 - i]) mr = false;
            if (in_sizes[i] != CANON[SORTED_ROLE[i]]) ms = false;
        }
        if (mc)      for (int c = 0; c < 19; ++c) perm[c] = c;
        else if (mr) for (int c = 0; c < 19; ++c) perm[c] = 18 - c;
        else if (ms) { for (int p = 0; p < 19; ++p) perm[SORTED_ROLE[p]] = p; }
        else         for (int c = 0; c < 19; ++c) perm[c] = c;  // best effort
    }
    if (!ok) {
        zero_out_k<<<(OUT_N + 255) / 256, 256, 0, stream>>>(out, OUT_N);
        return;
    }

    const float* x  = (const float*)d_in[perm[0]];
    const int*   ei = (const int*)d_in[perm[1]];
    const float* gs = (const float*)d_in[perm[2]];
    const float* gh = (const float*)d_in[perm[3]];
    const float* cw[3] = { (const float*)d_in[perm[4]], (const float*)d_in[perm[6]], (const float*)d_in[perm[8]] };
    const float* cb[3] = { (const float*)d_in[perm[5]], (const float*)d_in[perm[7]], (const float*)d_in[perm[9]] };
    const float* sw1 = (const float*)d_in[perm[10]];
    const float* sb1 = (const float*)d_in[perm[11]];
    const float* sw2 = (const float*)d_in[perm[12]];
    const float* sb2 = (const float*)d_in[perm[13]];
    const float* hw1 = (const float*)d_in[perm[14]];
    const float* hb1 = (const float*)d_in[perm[15]];
    const float* hw2 = (const float*)d_in[perm[16]];
    const float* hb2 = (const float*)d_in[perm[17]];
    // temp_w (perm[18]) unused: temp>0 always; softmax monotone -> decisions unaffected

    // ---- ws layout: h bf16 + z bf16 + flags; agg lives in d_out's z region ----
    const size_t H_B    = (size_t)ZT * 2;      // 12,800,000
    const size_t FLAG_B = 200192;              // NN*4 padded to 256
    const size_t ACT_B  = 256;
    const size_t need = 2 * H_B + 6 * FLAG_B + ACT_B;   // ~26.8 MB
    if (ws_size < need) {
        zero_out_k<<<(OUT_N + 255) / 256, 256, 0, stream>>>(out, OUT_N);
        return;
    }

    char* p = (char*)d_ws;
    u16* h   = (u16*)p; p += H_B;
    u16* zws = (u16*)p; p += H_B;
    int* deg    = (int*)p; p += FLAG_B;
    int* degns  = (int*)p; p += FLAG_B;
    int* ready  = (int*)p; p += FLAG_B;
    int* softex = (int*)p; p += FLAG_B;
    int* hardex = (int*)p; p += FLAG_B;
    int* exitl  = (int*)p; p += FLAG_B;
    int* act    = (int*)p; p += ACT_B;

    float* agg = out;   // d_out z region (ZT f32) reused as per-layer aggregation scratch

    init_k<<<(ZT + 255) / 256, 256, 0, stream>>>(x, h, deg, degns, softex, hardex, exitl, act);
    degree_k<<<(EE + 255) / 256, 256, 0, stream>>>(ei, deg, degns);

    for (int li = 0; li < LL; ++li) {
        int geluf = (li < LL - 1) ? 1 : 0;
        hipMemsetAsync(agg, 0, (size_t)ZT * 4, stream);
        scatter_f32_k<<<(EE * 32) / 256, 256, 0, stream>>>(ei, h, deg, agg);
        gemm_fin_k<<<(NN + GNB - 1) / GNB, 128, 0, stream>>>(geluf, h, agg, deg, cw[li], cb[li]);
        soft_head_k<<<(NN + NB - 1) / NB, 64, 0, stream>>>(li, h, sw1, sb1, sw2, sb2, gs, softex, hardex, act);
        hipMemsetAsync(ready, 0, (size_t)NN * 4, stream);
        ready_k<<<(EE + 255) / 256, 256, 0, stream>>>(ei, softex, ready);
        hard_head_k<<<(NN + NB - 1) / NB, 64, 0, stream>>>(li, h, hw1, hb1, hw2, hb2, gh, softex,
                                                           hardex, exitl, ready, degns, zws);
    }
    tail_k<<<(OUT_N + 255) / 256, 256, 0, stream>>>(h, zws, hardex, exitl, act, out);
}

// Round 6
// 828.334 us; speedup vs baseline: 5.6220x; 5.6220x over previous
//
#include <hip/hip_runtime.h>
#include <hip/hip_bf16.h>
#include <math.h>

#define NN 50000
#define EE 800000
#define HH 128
#define CHH 64
#define LL 3
#define ZT (NN * HH)
#define GNB 8
#define NB 16
#define SCB 512
#define NBLK 98          // ceil(50001/512)

using bf16 = __hip_bfloat16;
typedef unsigned short u16;
typedef unsigned int u32;

__device__ __forceinline__ float ldbf(const u16* p, size_t i) {
    return __uint_as_float(((u32)p[i]) << 16);
}
__device__ __forceinline__ void stbf(u16* p, size_t i, float v) {
    bf16 b = __float2bfloat16(v);
    p[i] = *reinterpret_cast<u16*>(&b);
}
__device__ __forceinline__ float blo(u32 w) { return __uint_as_float(w << 16); }
__device__ __forceinline__ float bhi(u32 w) { return __uint_as_float(w & 0xFFFF0000u); }

// ---- zero-fill fallback (diagnostic) ----
__global__ __launch_bounds__(256) void zero_out_k(float* __restrict__ out, int n) {
    int i = blockIdx.x * 256 + threadIdx.x;
    if (i < n) out[i] = 0.f;
}

// ---- init ----
__global__ __launch_bounds__(256) void init_k(const float* __restrict__ x, u16* __restrict__ h,
        int* __restrict__ deg, int* __restrict__ degns, int* __restrict__ softex,
        int* __restrict__ hardex, int* __restrict__ exitl, int* __restrict__ act) {
    int i = blockIdx.x * 256 + threadIdx.x;
    if (i < ZT) stbf(h, (size_t)i, x[i]);
    if (i < NN) { deg[i] = 1; degns[i] = 0; softex[i] = 0; hardex[i] = 0; exitl[i] = LL; }
    if (i < LL) act[i] = 0;
}

// ---- degrees ----
__global__ __launch_bounds__(256) void degree_k(const int* __restrict__ ei,
        int* __restrict__ deg, int* __restrict__ degns) {
    int e = blockIdx.x * 256 + threadIdx.x;
    if (e >= EE) return;
    int s = ei[e], d = ei[EE + e];
    if ((u32)s >= NN || (u32)d >= NN) return;
    atomicAdd(&deg[d], 1);
    if (s != d) atomicAdd(&degns[s], 1);
}

// ---- CSR build: scanA (block sums of in-degree) ----
__global__ __launch_bounds__(SCB) void scanA_k(const int* __restrict__ deg, int* __restrict__ bsum) {
    int t = threadIdx.x, g = blockIdx.x * SCB + t;
    __shared__ int s[SCB];
    s[t] = (g < NN) ? deg[g] - 1 : 0;
    __syncthreads();
    for (int off = SCB / 2; off > 0; off >>= 1) {
        if (t < off) s[t] += s[t + off];
        __syncthreads();
    }
    if (t == 0) bsum[blockIdx.x] = s[0];
}

// ---- scanB: exclusive scan of NBLK block sums ----
__global__ __launch_bounds__(128) void scanB_k(const int* __restrict__ bsum, int* __restrict__ boff) {
    int t = threadIdx.x;
    __shared__ int s[128];
    int v = (t < NBLK) ? bsum[t] : 0;
    s[t] = v;
    __syncthreads();
    for (int off = 1; off < 128; off <<= 1) {
        int x = (t >= off) ? s[t - off] : 0;
        __syncthreads();
        s[t] += x;
        __syncthreads();
    }
    if (t < NBLK) boff[t] = s[t] - v;
}

// ---- scanC: per-block exclusive scan + offset -> rowptr, cursor ----
__global__ __launch_bounds__(SCB) void scanC_k(const int* __restrict__ deg, const int* __restrict__ boff,
        int* __restrict__ rowptr, int* __restrict__ cursor) {
    int t = threadIdx.x, g = blockIdx.x * SCB + t;
    __shared__ int s[SCB];
    int v = (g < NN) ? deg[g] - 1 : 0;
    s[t] = v;
    __syncthreads();
    for (int off = 1; off < SCB; off <<= 1) {
        int x = (t >= off) ? s[t - off] : 0;
        __syncthreads();
        s[t] += x;
        __syncthreads();
    }
    int excl = s[t] - v + boff[blockIdx.x];
    if (g <= NN) rowptr[g] = excl;
    if (g < NN) cursor[g] = excl;
}

// ---- CSR fill: counting-sort edges by dst; precompute edge norm ----
__global__ __launch_bounds__(256) void fill_csr_k(const int* __restrict__ ei, const int* __restrict__ deg,
        int* __restrict__ cursor, int* __restrict__ csrc, float* __restrict__ cnrm) {
    int e = blockIdx.x * 256 + threadIdx.x;
    if (e >= EE) return;
    int s = ei[e], d = ei[EE + e];
    if ((u32)s >= NN || (u32)d >= NN) return;
    float nrm = 1.0f / sqrtf((float)deg[s] * (float)deg[d]);
    int pos = atomicAdd(&cursor[d], 1);
    csrc[pos] = s;
    cnrm[pos] = nrm;
}

// ---- gather aggregation: agg[n] = sum_in nrm * h[src]; 64 lanes/node, 2 ch/lane ----
__global__ __launch_bounds__(256) void gather_agg_k(const int* __restrict__ rowptr,
        const int* __restrict__ csrc, const float* __restrict__ cnrm,
        const u16* __restrict__ h, float* __restrict__ agg) {
    int node = blockIdx.x * 4 + (threadIdx.x >> 6);
    int lane = threadIdx.x & 63;
    if (node >= NN) return;
    int beg = rowptr[node], end = rowptr[node + 1];
    float a0 = 0.f, a1 = 0.f;
    int e = beg;
    for (; e + 1 < end; e += 2) {
        int s0 = csrc[e], s1 = csrc[e + 1];
        float n0 = cnrm[e], n1 = cnrm[e + 1];
        u32 w0 = *(const u32*)(h + (size_t)s0 * HH + lane * 2);
        u32 w1 = *(const u32*)(h + (size_t)s1 * HH + lane * 2);
        a0 = fmaf(n0, blo(w0), a0); a1 = fmaf(n0, bhi(w0), a1);
        a0 = fmaf(n1, blo(w1), a0); a1 = fmaf(n1, bhi(w1), a1);
    }
    if (e < end) {
        int s0 = csrc[e];
        float n0 = cnrm[e];
        u32 w0 = *(const u32*)(h + (size_t)s0 * HH + lane * 2);
        a0 = fmaf(n0, blo(w0), a0); a1 = fmaf(n0, bhi(w0), a1);
    }
    size_t o = (size_t)node * HH + lane * 2;
    agg[o] = a0;
    agg[o + 1] = a1;
}

// ---- FALLBACK scatter (atomics) for small ws ----
__global__ __launch_bounds__(256) void scatter_f32_k(const int* __restrict__ ei, const u16* __restrict__ h,
        const int* __restrict__ deg, float* __restrict__ agg) {
    int tid = blockIdx.x * 256 + threadIdx.x;
    int e = tid >> 5;
    if (e >= EE) return;
    int lane = tid & 31;
    int s = ei[e], d = ei[EE + e];
    if ((u32)s >= NN || (u32)d >= NN) return;
    float nrm = 1.0f / sqrtf((float)deg[s] * (float)deg[d]);
    size_t sb = (size_t)s * HH + lane * 4, db = (size_t)d * HH + lane * 4;
    const ushort4 hv = *(const ushort4*)(h + sb);
    atomicAdd(&agg[db + 0], nrm * __uint_as_float(((u32)hv.x) << 16));
    atomicAdd(&agg[db + 1], nrm * __uint_as_float(((u32)hv.y) << 16));
    atomicAdd(&agg[db + 2], nrm * __uint_as_float(((u32)hv.z) << 16));
    atomicAdd(&agg[db + 3], nrm * __uint_as_float(((u32)hv.w) << 16));
}

// ---- fused conv finish: h = act((agg + h/deg) @ W + b) in place ----
__global__ __launch_bounds__(128) void gemm_fin_k(int geluf, u16* __restrict__ h,
        const float* __restrict__ agg, const int* __restrict__ deg,
        const float* __restrict__ W, const float* __restrict__ b) {
    int bn = blockIdx.x * GNB;
    int o = threadIdx.x;
    __shared__ float c[GNB][HH];
    #pragma unroll
    for (int m = 0; m < GNB; ++m) {
        int n = bn + m;
        if (n < NN) c[m][o] = agg[(size_t)n * HH + o] + ldbf(h, (size_t)n * HH + o) / (float)deg[n];
    }
    __syncthreads();
    float acc[GNB];
    float bias = b[o];
    #pragma unroll
    for (int m = 0; m < GNB; ++m) acc[m] = bias;
    for (int k = 0; k < HH; ++k) {
        float w = W[k * HH + o];
        #pragma unroll
        for (int m = 0; m < GNB; ++m) acc[m] = fmaf(c[m][k], w, acc[m]);
    }
    #pragma unroll
    for (int m = 0; m < GNB; ++m) {
        int n = bn + m;
        if (n < NN) {
            float v = acc[m];
            if (geluf) v = 0.5f * v * (1.0f + erff(v * 0.70710678118654752f));
            stbf(h, (size_t)n * HH + o, v);
        }
    }
}

// ---- soft-exit head ----
__global__ __launch_bounds__(64) void soft_head_k(int li, const u16* __restrict__ h,
        const float* __restrict__ w1, const float* __restrict__ b1,
        const float* __restrict__ w2, const float* __restrict__ b2,
        const float* __restrict__ gs, int* __restrict__ softex,
        const int* __restrict__ hardex, int* __restrict__ act) {
    int bn = blockIdx.x * NB;
    int j = threadIdx.x;
    __shared__ float sh[NB][HH];
    for (int t = j; t < NB * HH; t += 64) {
        int m = t >> 7, k = t & 127, n = bn + m;
        sh[m][k] = (n < NN) ? ldbf(h, (size_t)n * HH + k) : 0.f;
    }
    __syncthreads();
    float acc[NB];
    float b1j = b1[j];
    #pragma unroll
    for (int m = 0; m < NB; ++m) acc[m] = b1j;
    for (int k = 0; k < HH; ++k) {
        float w = w1[k * CHH + j];
        #pragma unroll
        for (int m = 0; m < NB; ++m) acc[m] = fmaf(sh[m][k], w, acc[m]);
    }
    __shared__ float hid[NB][CHH + 1];
    #pragma unroll
    for (int m = 0; m < NB; ++m) hid[m][j] = fmaxf(acc[m], 0.f);
    __syncthreads();
    if (j < NB) {
        int n = bn + j;
        if (n < NN) {
            float l0 = b2[0], l1 = b2[1];
            for (int t = 0; t < CHH; ++t) {
                float hv = hid[j][t];
                l0 = fmaf(hv, w2[t * 2], l0);
                l1 = fmaf(hv, w2[t * 2 + 1], l1);
            }
            const float* g = gs + ((size_t)li * NN + n) * 2;
            if (l1 + g[1] > l0 + g[0]) softex[n] = 1;
            if (!hardex[n]) atomicAdd(&act[li], 1);  // counted before this layer's hard exits
        }
    }
}

// ---- readiness scatter ----
__global__ __launch_bounds__(256) void ready_k(const int* __restrict__ ei,
        const int* __restrict__ softex, int* __restrict__ ready) {
    int e = blockIdx.x * 256 + threadIdx.x;
    if (e >= EE) return;
    int s = ei[e], d = ei[EE + e];
    if ((u32)s >= NN || (u32)d >= NN) return;
    if (s != d && softex[d]) atomicAdd(&ready[s], 1);
}

// ---- hard-exit head; exited rows snapshot into bf16 zws ----
__global__ __launch_bounds__(64) void hard_head_k(int li, const u16* __restrict__ h,
        const float* __restrict__ w1, const float* __restrict__ b1,
        const float* __restrict__ w2, const float* __restrict__ b2,
        const float* __restrict__ gh, const int* __restrict__ softex,
        int* __restrict__ hardex, int* __restrict__ exitl,
        const int* __restrict__ ready, const int* __restrict__ degns,
        u16* __restrict__ zws) {
    int bn = blockIdx.x * NB;
    int j = threadIdx.x;
    __shared__ int elig[NB];
    __shared__ float rd[NB];
    if (j < NB) {
        int n = bn + j;
        int e = (n < NN) && softex[n] && !hardex[n];
        elig[j] = e;
        float r = 0.f;
        if (e) {
            int dns = degns[n]; if (dns < 1) dns = 1;
            r = (float)ready[n] / (float)dns;
        }
        rd[j] = r;
    }
    __syncthreads();
    int any = 0;
    #pragma unroll
    for (int m = 0; m < NB; ++m) any |= elig[m];
    if (!any) return;
    __shared__ float sh[NB][HH];
    for (int t = j; t < NB * HH; t += 64) {
        int m = t >> 7, k = t & 127, n = bn + m;
        sh[m][k] = elig[m] ? ldbf(h, (size_t)n * HH + k) : 0.f;
    }
    __syncthreads();
    float acc[NB];
    float b1j = b1[j];
    #pragma unroll
    for (int m = 0; m < NB; ++m) acc[m] = b1j;
    for (int k = 0; k < HH; ++k) {
        float w = w1[k * CHH + j];
        #pragma unroll
        for (int m = 0; m < NB; ++m) acc[m] = fmaf(sh[m][k], w, acc[m]);
    }
    float wr = w1[HH * CHH + j];
    #pragma unroll
    for (int m = 0; m < NB; ++m) acc[m] = fmaf(rd[m], wr, acc[m]);
    __shared__ float hid[NB][CHH + 1];
    __shared__ int ex[NB];
    #pragma unroll
    for (int m = 0; m < NB; ++m) hid[m][j] = fmaxf(acc[m], 0.f);
    if (j < NB) ex[j] = 0;
    __syncthreads();
    if (j < NB) {
        int n = bn + j;
        if (elig[j]) {
            float l0 = b2[0], l1 = b2[1];
            for (int t = 0; t < CHH; ++t) {
                float hv = hid[j][t];
                l0 = fmaf(hv, w2[t * 2], l0);
                l1 = fmaf(hv, w2[t * 2 + 1], l1);
            }
            const float* g = gh + ((size_t)li * NN + n) * 2;
            if (l1 + g[1] > l0 + g[0]) { ex[j] = 1; hardex[n] = 1; exitl[n] = li; }
        }
    }
    __syncthreads();
    #pragma unroll
    for (int m = 0; m < NB; ++m) {
        if (ex[m]) {
            int n = bn + m;
            for (int k = j; k < HH; k += 64)
                stbf(zws, (size_t)n * HH + k, sh[m][k]);
        }
    }
}

// ---- tail: f32 outputs ----
__global__ __launch_bounds__(256) void tail_k(const u16* __restrict__ h, const u16* __restrict__ zws,
        const int* __restrict__ hardex, const int* __restrict__ exitl, const int* __restrict__ act,
        float* __restrict__ out) {
    int i = blockIdx.x * 256 + threadIdx.x;
    if (i < ZT) {
        int n = i >> 7;
        out[i] = hardex[n] ? ldbf(zws, (size_t)i) : ldbf(h, (size_t)i);
    } else if (i < ZT + NN) {
        out[i] = (float)exitl[i - ZT];
    } else if (i < ZT + NN + LL) {
        out[i] = (float)act[i - ZT - NN];
    }
}

extern "C" void kernel_launch(void* const* d_in, const int* in_sizes, int n_in,
                              void* d_out, int out_size, void* d_ws, size_t ws_size,
                              hipStream_t stream) {
    float* out = (float*)d_out;                 // output is FLOAT32
    const int OUT_N = ZT + NN + LL;

    static const int CANON[19] = {6400000,1600000,300000,300000,16384,128,16384,128,16384,128,
                                  8192,64,128,2,8256,64,128,2,128};
    static const int SORTED_ROLE[19] = {5,7,9,4,6,8,1,3,2,15,17,14,16,11,13,10,12,18,0};
    int perm[19];
    bool ok = (n_in == 19);
    if (ok) {
        bool mc = true, mr = true, ms = true;
        for (int i = 0; i < 19; ++i) {
            if (in_sizes[i] != CANON[i]) mc = false;
            if (in_sizes[i] != CANON[18 - i]) mr = false;
            if (in_sizes[i] != CANON[SORTED_ROLE[i]]) ms = false;
        }
        if (mc)      for (int c = 0; c < 19; ++c) perm[c] = c;
        else if (mr) for (int c = 0; c < 19; ++c) perm[c] = 18 - c;
        else if (ms) { for (int p = 0; p < 19; ++p) perm[SORTED_ROLE[p]] = p; }
        else         for (int c = 0; c < 19; ++c) perm[c] = c;
    }
    if (!ok) {
        zero_out_k<<<(OUT_N + 255) / 256, 256, 0, stream>>>(out, OUT_N);
        return;
    }

    const float* x  = (const float*)d_in[perm[0]];
    const int*   ei = (const int*)d_in[perm[1]];
    const float* gs = (const float*)d_in[perm[2]];
    const float* gh = (const float*)d_in[perm[3]];
    const float* cw[3] = { (const float*)d_in[perm[4]], (const float*)d_in[perm[6]], (const float*)d_in[perm[8]] };
    const float* cb[3] = { (const float*)d_in[perm[5]], (const float*)d_in[perm[7]], (const float*)d_in[perm[9]] };
    const float* sw1 = (const float*)d_in[perm[10]];
    const float* sb1 = (const float*)d_in[perm[11]];
    const float* sw2 = (const float*)d_in[perm[12]];
    const float* sb2 = (const float*)d_in[perm[13]];
    const float* hw1 = (const float*)d_in[perm[14]];
    const float* hb1 = (const float*)d_in[perm[15]];
    const float* hw2 = (const float*)d_in[perm[16]];
    const float* hb2 = (const float*)d_in[perm[17]];
    // temp_w unused: temp>0 always; softmax monotone -> decisions unaffected

    const size_t H_B    = (size_t)ZT * 2;      // 12,800,000
    const size_t FLAG_B = 200192;
    const size_t ACT_B  = 256;
    const size_t RP_B   = 51200 * 4;           // rowptr (NN+1, padded)
    const size_t BS_B   = 512;                 // bsum / boff
    const size_t CSRC_B = (size_t)EE * 4;
    const size_t CNRM_B = (size_t)EE * 4;
    const size_t base_need = 2 * H_B + 6 * FLAG_B + ACT_B;                     // ~26.8 MB
    const size_t csr_need  = base_need + RP_B + BS_B * 2 + CSRC_B + CNRM_B;    // ~33.6 MB

    const bool useCSR = ws_size >= csr_need;
    if (!useCSR && ws_size < base_need) {
        zero_out_k<<<(OUT_N + 255) / 256, 256, 0, stream>>>(out, OUT_N);
        return;
    }

    char* p = (char*)d_ws;
    u16* h   = (u16*)p; p += H_B;
    u16* zws = (u16*)p; p += H_B;
    int* deg    = (int*)p; p += FLAG_B;
    int* degns  = (int*)p; p += FLAG_B;
    int* ready  = (int*)p; p += FLAG_B;
    int* softex = (int*)p; p += FLAG_B;
    int* hardex = (int*)p; p += FLAG_B;
    int* exitl  = (int*)p; p += FLAG_B;
    int* act    = (int*)p; p += ACT_B;
    int* rowptr = nullptr; int* bsum = nullptr; int* boff = nullptr;
    int* csrc = nullptr; float* cnrm = nullptr; int* cursor = nullptr;
    if (useCSR) {
        rowptr = (int*)p; p += RP_B;
        bsum   = (int*)p; p += BS_B;
        boff   = (int*)p; p += BS_B;
        csrc   = (int*)p; p += CSRC_B;
        cnrm   = (float*)p; p += CNRM_B;
        cursor = ready;   // reuse: cursor consumed by fill_csr before ready_k ever runs? NO -
                          // cursor is used only during build (before layer loop); ready is
                          // memset before each ready_k. Safe to alias.
    }

    float* agg = out;   // d_out z region reused as per-layer aggregation scratch

    init_k<<<(ZT + 255) / 256, 256, 0, stream>>>(x, h, deg, degns, softex, hardex, exitl, act);
    degree_k<<<(EE + 255) / 256, 256, 0, stream>>>(ei, deg, degns);

    if (useCSR) {
        scanA_k<<<NBLK, SCB, 0, stream>>>(deg, bsum);
        scanB_k<<<1, 128, 0, stream>>>(bsum, boff);
        scanC_k<<<NBLK, SCB, 0, stream>>>(deg, boff, rowptr, cursor);
        fill_csr_k<<<(EE + 255) / 256, 256, 0, stream>>>(ei, deg, cursor, csrc, cnrm);
    }

    for (int li = 0; li < LL; ++li) {
        int geluf = (li < LL - 1) ? 1 : 0;
        if (useCSR) {
            gather_agg_k<<<(NN + 3) / 4, 256, 0, stream>>>(rowptr, csrc, cnrm, h, agg);
        } else {
            hipMemsetAsync(agg, 0, (size_t)ZT * 4, stream);
            scatter_f32_k<<<(EE * 32) / 256, 256, 0, stream>>>(ei, h, deg, agg);
        }
        gemm_fin_k<<<(NN + GNB - 1) / GNB, 128, 0, stream>>>(geluf, h, agg, deg, cw[li], cb[li]);
        soft_head_k<<<(NN + NB - 1) / NB, 64, 0, stream>>>(li, h, sw1, sb1, sw2, sb2, gs, softex, hardex, act);
        hipMemsetAsync(ready, 0, (size_t)NN * 4, stream);
        ready_k<<<(EE + 255) / 256, 256, 0, stream>>>(ei, softex, ready);
        hard_head_k<<<(NN + NB - 1) / NB, 64, 0, stream>>>(li, h, hw1, hb1, hw2, hb2, gh, softex,
                                                           hardex, exitl, ready, degns, zws);
    }
    tail_k<<<(OUT_N + 255) / 256, 256, 0, stream>>>(h, zws, hardex, exitl, act, out);
}